// Round 2
// baseline (379.709 us; speedup 1.0000x reference)
//
#include <hip/hip_runtime.h>

constexpr int L = 128;

// Tile: 32 pixels along k (x-fastest, coalesced stores) x 16 pixels along j.
// 256 threads, 2 pixels per thread (j and j+8). A wave (64 lanes) covers two
// adjacent j-rows of 32 k -> compact sampling footprint; the whole tile's
// volume patch (~55x28x3 voxels ~ 18 KB) fits in L1, so lines fetched for one
// row are reused by the other 15 rows instead of being re-fetched from L3.
__global__ __launch_bounds__(256) void xfel_proj(
    const float* __restrict__ rotmat,   // [B,3,3]
    const float* __restrict__ vol,      // [L,L,L] as [D,H,W]
    float* __restrict__ out)            // [B,L,L]
{
    const int tid = threadIdx.x;
    const int kl  = tid & 31;
    const int jl  = tid >> 5;                    // 0..7
    const int tile = blockIdx.x;                 // 0..31: 4 k-tiles x 8 j-tiles
    const int b    = blockIdx.y;
    const int k     = ((tile & 3) << 5) | kl;
    const int jbase = ((tile >> 2) << 4) | jl;

    // rotation is block-uniform -> scalar loads
    const float* __restrict__ R = rotmat + b * 9;
    const float R00 = R[0], R01 = R[1], R02 = R[2];
    const float R10 = R[3], R11 = R[4], R12 = R[5];
    const float R20 = R[6], R21 = R[7], R22 = R[8];

    const float lk = -1.0f + (float)k * (2.0f / 127.0f);
    const float yc = -1.0f + 64.0f * (2.0f / 127.0f);   // lin[64]
    // j-independent part of the rotated point
    const float cx = yc * R10 + lk * R20;
    const float cy = yc * R11 + lk * R21;
    const float cz = yc * R12 + lk * R22;

    const float ak  = (float)(k - 64) * (128.0f / 127.0f);
    const float thr = 57.6f * 57.6f;                    // (0.9*L/2)^2

    #pragma unroll
    for (int m = 0; m < 2; ++m) {
        const int j = jbase + (m << 3);
        const int oidx = (b * L + j) * L + k;
        float res = 0.0f;

        const float aj = (float)(j - 64) * (128.0f / 127.0f);
        if (aj * aj + ak * ak < thr) {                  // circular mask
            const float lj = -1.0f + (float)j * (2.0f / 127.0f);
            // grid_sample align_corners=True: voxel coords
            const float gx = (lj * R00 + cx + 1.0f) * 63.5f;
            const float gy = (lj * R01 + cy + 1.0f) * 63.5f;
            const float gz = (lj * R02 + cz + 1.0f) * 63.5f;

            const float fx0 = floorf(gx), fy0 = floorf(gy), fz0 = floorf(gz);
            const int ix = (int)fx0, iy = (int)fy0, iz = (int)fz0;

            if (ix >= -1 && ix < L && iy >= -1 && iy < L && iz >= -1 && iz < L) {
                const float fx = gx - fx0, fy = gy - fy0, fz = gz - fz0;
                // per-corner validity folded into weights (zeros padding)
                const float wx0 = (ix >= 0)    ? (1.0f - fx) : 0.0f;
                const float wx1 = (ix + 1 < L) ? fx          : 0.0f;
                const float wy0 = (iy >= 0)    ? (1.0f - fy) : 0.0f;
                const float wy1 = (iy + 1 < L) ? fy          : 0.0f;
                const float wz0 = (iz >= 0)    ? (1.0f - fz) : 0.0f;
                const float wz1 = (iz + 1 < L) ? fz          : 0.0f;

                const int x0 = max(ix, 0), x1 = min(ix + 1, L - 1);
                const int y0 = max(iy, 0), y1 = min(iy + 1, L - 1);
                const int z0 = max(iz, 0), z1 = min(iz + 1, L - 1);

                const float* __restrict__ p0 = vol + z0 * L * L;
                const float* __restrict__ p1 = vol + z1 * L * L;
                const float v000 = p0[y0 * L + x0];
                const float v001 = p0[y0 * L + x1];
                const float v010 = p0[y1 * L + x0];
                const float v011 = p0[y1 * L + x1];
                const float v100 = p1[y0 * L + x0];
                const float v101 = p1[y0 * L + x1];
                const float v110 = p1[y1 * L + x0];
                const float v111 = p1[y1 * L + x1];

                const float r0 = wy0 * (wx0 * v000 + wx1 * v001)
                               + wy1 * (wx0 * v010 + wx1 * v011);
                const float r1 = wy0 * (wx0 * v100 + wx1 * v101)
                               + wy1 * (wx0 * v110 + wx1 * v111);
                res = wz0 * r0 + wz1 * r1;
            }
        }
        __builtin_nontemporal_store(res, out + oidx);
    }
}

extern "C" void kernel_launch(void* const* d_in, const int* in_sizes, int n_in,
                              void* d_out, int out_size, void* d_ws, size_t ws_size,
                              hipStream_t stream) {
    const float* rotmat = (const float*)d_in[0];
    const float* vol    = (const float*)d_in[1];
    float* out          = (float*)d_out;
    const int B = in_sizes[0] / 9;               // 2048
    dim3 grid(32, B);                            // 32 tiles of 32x16 per image
    xfel_proj<<<grid, dim3(256), 0, stream>>>(rotmat, vol, out);
}

// Round 3
// 314.710 us; speedup vs baseline: 1.2065x; 1.2065x over previous
//
#include <hip/hip_runtime.h>

constexpr int L = 128;

// Tile: 64 pixels along k x 16 along j. Block = 256 threads = 4 waves.
// lane (tid&63) -> k offset, so every gather instruction is a wave of 64
// CONSECUTIVE k in ONE image row (compact line footprint, R1's pattern).
// Each thread computes 4 rows (w, w+4, w+8, w+12), fully unrolled -> ~32
// independent vol loads in flight per thread to cover L2/L3 miss latency.
__global__ __launch_bounds__(256) void xfel_proj(
    const float* __restrict__ rotmat,   // [B,3,3]
    const float* __restrict__ vol,      // [L,L,L] as [D,H,W]
    float* __restrict__ out)            // [B,L,L]
{
    const int tid  = threadIdx.x;
    const int lane = tid & 63;
    const int w    = tid >> 6;                   // 0..3
    const int t    = blockIdx.x;                 // 0..15: 2 k-tiles x 8 j-tiles
    const int b    = blockIdx.y;
    const int k    = ((t & 1) << 6) | lane;
    const int j0   = (((t >> 1) << 4)) + w;      // this thread's base row

    // rotation is block-uniform -> scalar loads
    const float* __restrict__ R = rotmat + b * 9;
    const float R00 = R[0], R01 = R[1], R02 = R[2];
    const float R10 = R[3], R11 = R[4], R12 = R[5];
    const float R20 = R[6], R21 = R[7], R22 = R[8];

    const float lk = -1.0f + (float)k * (2.0f / 127.0f);
    const float yc = -1.0f + 64.0f * (2.0f / 127.0f);   // lin[64]
    // j-independent part of rotated point (+1, *63.5 folded in later)
    const float cx = yc * R10 + lk * R20;
    const float cy = yc * R11 + lk * R21;
    const float cz = yc * R12 + lk * R22;

    const float ak  = (float)(k - 64) * (128.0f / 127.0f);
    const float ak2 = ak * ak;
    const float thr = 57.6f * 57.6f;                    // (0.9*L/2)^2

    #pragma unroll
    for (int m = 0; m < 4; ++m) {
        const int j = j0 + (m << 2);
        const int oidx = (b * L + j) * L + k;
        float res = 0.0f;

        const float aj = (float)(j - 64) * (128.0f / 127.0f);
        if (aj * aj + ak2 < thr) {                      // circular mask
            const float lj = -1.0f + (float)j * (2.0f / 127.0f);
            // grid_sample align_corners=True voxel coords
            const float gx = (lj * R00 + cx + 1.0f) * 63.5f;
            const float gy = (lj * R01 + cy + 1.0f) * 63.5f;
            const float gz = (lj * R02 + cz + 1.0f) * 63.5f;

            const float fx0 = floorf(gx), fy0 = floorf(gy), fz0 = floorf(gz);
            const int ix = (int)fx0, iy = (int)fy0, iz = (int)fz0;

            if (ix >= -1 && ix < L && iy >= -1 && iy < L && iz >= -1 && iz < L) {
                const float fx = gx - fx0, fy = gy - fy0, fz = gz - fz0;
                // per-corner validity folded into weights (zeros padding)
                const float wx0 = (ix >= 0)    ? (1.0f - fx) : 0.0f;
                const float wx1 = (ix + 1 < L) ? fx          : 0.0f;
                const float wy0 = (iy >= 0)    ? (1.0f - fy) : 0.0f;
                const float wy1 = (iy + 1 < L) ? fy          : 0.0f;
                const float wz0 = (iz >= 0)    ? (1.0f - fz) : 0.0f;
                const float wz1 = (iz + 1 < L) ? fz          : 0.0f;

                const int x0 = max(ix, 0), x1 = min(ix + 1, L - 1);
                const int y0 = max(iy, 0), y1 = min(iy + 1, L - 1);
                const int z0 = max(iz, 0), z1 = min(iz + 1, L - 1);

                const float* __restrict__ p0 = vol + z0 * L * L;
                const float* __restrict__ p1 = vol + z1 * L * L;
                const float v000 = p0[y0 * L + x0];
                const float v001 = p0[y0 * L + x1];
                const float v010 = p0[y1 * L + x0];
                const float v011 = p0[y1 * L + x1];
                const float v100 = p1[y0 * L + x0];
                const float v101 = p1[y0 * L + x1];
                const float v110 = p1[y1 * L + x0];
                const float v111 = p1[y1 * L + x1];

                const float r0 = wy0 * (wx0 * v000 + wx1 * v001)
                               + wy1 * (wx0 * v010 + wx1 * v011);
                const float r1 = wy0 * (wx0 * v100 + wx1 * v101)
                               + wy1 * (wx0 * v110 + wx1 * v111);
                res = wz0 * r0 + wz1 * r1;
            }
        }
        __builtin_nontemporal_store(res, out + oidx);
    }
}

extern "C" void kernel_launch(void* const* d_in, const int* in_sizes, int n_in,
                              void* d_out, int out_size, void* d_ws, size_t ws_size,
                              hipStream_t stream) {
    const float* rotmat = (const float*)d_in[0];
    const float* vol    = (const float*)d_in[1];
    float* out          = (float*)d_out;
    const int B = in_sizes[0] / 9;               // 2048
    dim3 grid(16, B);                            // 16 tiles of 64x16 per image
    xfel_proj<<<grid, dim3(256), 0, stream>>>(rotmat, vol, out);
}